// Round 12
// baseline (245.729 us; speedup 1.0000x reference)
//
#include <hip/hip_runtime.h>
#include <hip/hip_bf16.h>
#include <math.h>

#define N_ROWS 4096
#define DIM    512            // bytes per fp8 row == elements
#define M_ROWS 8192
// sim GEMM: 128x128 tiles, 4 waves (2x2 of 64x64), FP8 e4m3, BK=64,
// 8 K-steps (vs 16 at bf16), 32 KB LDS dbuf, counted-vmcnt loop.
#define NB     2080           // 64*65/2 triangular tiles (2080 % 8 == 0)
#define NSTEP  8              // 512 / 64
// exp(sim/0.1) = exp2(sim * 10*log2(e))
#define EXP_SCALE 14.4269504088896340736f

typedef unsigned char u8;
typedef unsigned long long u64;
typedef __attribute__((ext_vector_type(4))) float f32x4;

// float -> fp8 e4m3fn (OCP), round-to-nearest-even. Inputs finite, |x| <= 1.
__device__ __forceinline__ unsigned int f2e4m3(float x) {
  unsigned int b = __float_as_uint(x);
  unsigned int s = (b >> 24) & 0x80u;
  int e = (int)((b >> 23) & 0xffu);
  unsigned int m = b & 0x7fffffu;
  int ne = e - 127 + 7;                 // target biased exponent
  unsigned int out;
  if (ne >= 1) {                        // normal (|x| >= 2^-6)
    unsigned int q = ((unsigned int)ne << 3) | (m >> 20);
    unsigned int rem = m & 0xfffffu;
    unsigned int rnd = (rem > 0x80000u) || ((rem == 0x80000u) && (q & 1u));
    out = q + rnd;                      // |x|<=1 -> no overflow into NaN
  } else {                              // subnormal / underflow (2^-9 lsb)
    int sh = 21 - ne;                   // 20 + (1 - ne) >= 21
    if (sh > 24) {
      out = 0;
    } else {
      unsigned int full = 0x800000u | m;
      unsigned int q = full >> sh;
      unsigned int rem = full & ((1u << sh) - 1u);
      unsigned int half = 1u << (sh - 1);
      unsigned int rnd = (rem > half) || ((rem == half) && (q & 1u));
      out = q + rnd;
    }
  }
  return s | out;
}

__device__ __forceinline__ unsigned int pack4fp8(float4 v, float s) {
  return f2e4m3(v.x * s) | (f2e4m3(v.y * s) << 8) |
         (f2e4m3(v.z * s) << 16) | (f2e4m3(v.w * s) << 24);
}

// async global -> LDS, 16 B/lane (lds dest = wave-uniform base + lane*16)
__device__ __forceinline__ void async16(const u8* g, u8* l) {
  __builtin_amdgcn_global_load_lds(
      (const __attribute__((address_space(1))) void*)g,
      (__attribute__((address_space(3))) void*)l,
      16, 0, 0);
}

// ---------------------------------------------------------------------------
// Kernel 1: per-row L2 normalize -> fp8 e4m3 reps[8192][512]; exact fp32
// pos[i] = dot(z_i, z_j). Also zeroes denom[] and the done-counter.
// ---------------------------------------------------------------------------
__global__ __launch_bounds__(256) void norm_kernel(
    const float* __restrict__ ei, const float* __restrict__ ej,
    u8* __restrict__ reps, float* __restrict__ pos,
    float* __restrict__ denom, unsigned int* __restrict__ ctr) {
  int wave = threadIdx.x >> 6;
  int lane = threadIdx.x & 63;
  int b = blockIdx.x * 4 + wave;
  if (blockIdx.x == 0 && threadIdx.x == 0) *ctr = 0u;
  if (lane == 0) {
    denom[b] = 0.0f;
    denom[b + N_ROWS] = 0.0f;
  }
  const float4* pi = (const float4*)(ei + (size_t)b * DIM);
  const float4* pj = (const float4*)(ej + (size_t)b * DIM);
  float4 a0 = pi[lane];
  float4 a1 = pi[lane + 64];
  float4 b0 = pj[lane];
  float4 b1 = pj[lane + 64];

  float si = a0.x*a0.x + a0.y*a0.y + a0.z*a0.z + a0.w*a0.w
           + a1.x*a1.x + a1.y*a1.y + a1.z*a1.z + a1.w*a1.w;
  float sj = b0.x*b0.x + b0.y*b0.y + b0.z*b0.z + b0.w*b0.w
           + b1.x*b1.x + b1.y*b1.y + b1.z*b1.z + b1.w*b1.w;
  float dp = a0.x*b0.x + a0.y*b0.y + a0.z*b0.z + a0.w*b0.w
           + a1.x*b1.x + a1.y*b1.y + a1.z*b1.z + a1.w*b1.w;

#pragma unroll
  for (int m = 32; m >= 1; m >>= 1) {
    si += __shfl_xor(si, m, 64);
    sj += __shfl_xor(sj, m, 64);
    dp += __shfl_xor(dp, m, 64);
  }
  float ii = 1.0f / fmaxf(sqrtf(si), 1e-12f);
  float ij = 1.0f / fmaxf(sqrtf(sj), 1e-12f);
  if (lane == 0) pos[b] = dp * ii * ij;

  // fp8 row = 512 B = 128 dwords; a0 covers elems lane*4..+3 -> dword lane,
  // a1 covers 256+lane*4 -> dword 64+lane. Coalesced 4-B stores.
  unsigned int* ri = (unsigned int*)(reps + (size_t)b * DIM);
  unsigned int* rj = (unsigned int*)(reps + (size_t)(b + N_ROWS) * DIM);
  ri[lane]      = pack4fp8(a0, ii);
  ri[lane + 64] = pack4fp8(a1, ii);
  rj[lane]      = pack4fp8(b0, ij);
  rj[lane + 64] = pack4fp8(b1, ij);
}

// ---------------------------------------------------------------------------
// Kernel 2: 128x128-tile fused FP8 sim-GEMM + exp + masked row/col reduction
// + fused final loss (last block). Rounds 0-11 post-mortem: sim pinned at
// 72-82 us across tile/bytes/cache/schedule/occupancy/layout -> per-K-step
// cost is the invariant. FP8 halves the step count (BK=64, 8 steps) at the
// same per-step staging volume and same MFMA count (fp8 16x16x32 = bf16
// rate). Counted-vmcnt stage-at-top loop as round 8 (verified absmax 0).
// LDS swizzle for 64-B rows, 16-B granule: slot t ^= row&3 on both sides
// (staging source pre-swizzle + ds_read addr) -> reads hit all 32 banks
// (bandwidth floor, no conflicts). Frag k-mapping: lane quad q holds
// k = ks*32 + q*8 .. +8 -> 8-B slot (ks*2 + (q>>1), half q&1).
// ---------------------------------------------------------------------------
__global__ __launch_bounds__(256) void sim_kernel(
    const u8* __restrict__ reps, float* __restrict__ denom,
    const float* __restrict__ pos, float* __restrict__ out,
    unsigned int* __restrict__ ctr) {
  // chunked XCD remap: XCD x owns logical ids [x*260, (x+1)*260)
  int id = blockIdx.x;
  id = (id & 7) * (NB / 8) + (id >> 3);

  // super-tile blob decode: 4x4 super grid (16x16 tiles each), sj-major,
  // si<=sj; diag super = 136 tiles (16x16 triangle), off-diag = 256.
  int bi, bj;
  {
    int rem = id, Si = 0, Sj = 0, fnd = 0;
    for (int s_j = 0; s_j < 4 && !fnd; ++s_j)
      for (int s_i = 0; s_i <= s_j && !fnd; ++s_i) {
        int sz = (s_i == s_j) ? 136 : 256;
        if (rem < sz) { Si = s_i; Sj = s_j; fnd = 1; }
        else rem -= sz;
      }
    if (Si == Sj) {
      int tj = 0;
      while ((tj + 1) * (tj + 2) / 2 <= rem) ++tj;   // tj <= 15
      int ti = rem - tj * (tj + 1) / 2;
      bi = Si * 16 + ti;
      bj = Sj * 16 + tj;
    } else {
      bi = Si * 16 + (rem & 15);
      bj = Sj * 16 + (rem >> 4);
    }
  }

  __shared__ u8 As[2][8192];   // 8 KB per buffer (128 rows x 64 B)
  __shared__ u8 Bs[2][8192];   // total 32 KB
  __shared__ float red[4];
  __shared__ int lastflag;

  int tid  = threadIdx.x;
  int wave = tid >> 6, lane = tid & 63;
  int wr = wave >> 1, wc = wave & 1;     // 2x2 wave grid, 64x64 each
  int quad = lane >> 4, l15 = lane & 15;

  // staging: chunk c covers LDS bytes [c*1024, c*1024+1024) = rows c*16..+15
  // (64 B per row per step). Source col pre-swizzled at 16-B granule so the
  // linear LDS dest holds row r's slot t at (t ^ (r&3)).
  int c0 = wave * 2, c1 = c0 + 1;
  int srow = lane >> 2;                       // row within 16-row chunk
  int scol = ((lane & 3) ^ (srow & 3)) * 16;  // swizzled 16-B slot offset
  const u8* gA0 = reps + (size_t)(bi * 128 + c0 * 16 + srow) * DIM + scol;
  const u8* gA1 = reps + (size_t)(bi * 128 + c1 * 16 + srow) * DIM + scol;
  const u8* gB0 = reps + (size_t)(bj * 128 + c0 * 16 + srow) * DIM + scol;
  const u8* gB1 = reps + (size_t)(bj * 128 + c1 * 16 + srow) * DIM + scol;

#define STAGE(D, KC) do {                              \
    int o_ = (KC) * 64;                                \
    async16(gA0 + o_, &As[D][c0 * 1024]);              \
    async16(gA1 + o_, &As[D][c1 * 1024]);              \
    async16(gB0 + o_, &Bs[D][c0 * 1024]);              \
    async16(gB1 + o_, &Bs[D][c1 * 1024]);              \
  } while (0)

  // fragment read offsets: row = (16-mult)+l15, slot t = ks*2 + (quad>>1),
  // swizzled t^(l15&3), half (quad&1)*8.
  int qh = quad >> 1, ql = quad & 1, x2 = l15 & 3;
  int sw0 = ((qh ^ x2) * 16) + ql * 8;         // ks = 0
  int sw1 = (((2 + qh) ^ x2) * 16) + ql * 8;   // ks = 1
  int abase = (wr * 64 + l15) * 64;
  int bbase = (wc * 64 + l15) * 64;

  f32x4 zero4 = {0.0f, 0.0f, 0.0f, 0.0f};
  f32x4 acc[4][4];
#pragma unroll
  for (int tr = 0; tr < 4; ++tr)
#pragma unroll
    for (int tc = 0; tc < 4; ++tc) acc[tr][tc] = zero4;

  // prologue: stage k-step 0 into buffer 0
  STAGE(0, 0);

  for (int kk = 0; kk < NSTEP; ++kk) {
    int cur = kk & 1;
    int nc = (kk + 1) & 7;   // wrap at kk=7: dummy stage, never read

    STAGE(cur ^ 1, nc);
    asm volatile("s_waitcnt vmcnt(4)" ::: "memory");
    __builtin_amdgcn_s_barrier();   // buf[cur] valid for all waves

    const u8* Ah = &As[cur][0];
    const u8* Bh = &Bs[cur][0];
    long aF[4][2], bF[4][2];
#pragma unroll
    for (int t = 0; t < 4; ++t) {
      aF[t][0] = *(const long*)(Ah + abase + t * 1024 + sw0);
      aF[t][1] = *(const long*)(Ah + abase + t * 1024 + sw1);
      bF[t][0] = *(const long*)(Bh + bbase + t * 1024 + sw0);
      bF[t][1] = *(const long*)(Bh + bbase + t * 1024 + sw1);
    }
    __builtin_amdgcn_s_setprio(1);
#pragma unroll
    for (int ks = 0; ks < 2; ++ks)
#pragma unroll
      for (int tr = 0; tr < 4; ++tr)
#pragma unroll
        for (int tc = 0; tc < 4; ++tc)
          acc[tr][tc] = __builtin_amdgcn_mfma_f32_16x16x32_fp8_fp8(
              aF[tr][ks], bF[tc][ks], acc[tr][tc], 0, 0, 0);
    __builtin_amdgcn_s_setprio(0);
    __builtin_amdgcn_s_barrier();   // reads of buf[cur] done before overwrite
  }
  // drain the kk=7 dummy stages
  asm volatile("s_waitcnt vmcnt(0)" ::: "memory");

  // ---- epilogue: e = exp(sim/T), mask diagonal, row + col sums ----
  // C/D layout per 16x16 frag (dtype-independent): col=l15, row=quad*4+r
  int rowg_base = bi * 128 + wr * 64;
  int colg_base = bj * 128 + wc * 64;

  f32x4 rsum[4];
  float csum[4] = {0.0f, 0.0f, 0.0f, 0.0f};
#pragma unroll
  for (int tr = 0; tr < 4; ++tr) rsum[tr] = zero4;

#pragma unroll
  for (int tr = 0; tr < 4; ++tr) {
    int rowg0 = rowg_base + tr * 16 + quad * 4;
#pragma unroll
    for (int tc = 0; tc < 4; ++tc) {
      int colg = colg_base + tc * 16 + l15;
      f32x4 a = acc[tr][tc];
      f32x4 e;
#pragma unroll
      for (int r = 0; r < 4; ++r) {
        float v = exp2f(a[r] * EXP_SCALE);
        e[r] = ((rowg0 + r) == colg) ? 0.0f : v;
      }
      rsum[tr] += e;
      csum[tc] += e[0] + e[1] + e[2] + e[3];
    }
  }

#pragma unroll
  for (int m = 1; m <= 8; m <<= 1)
#pragma unroll
    for (int tr = 0; tr < 4; ++tr)
#pragma unroll
      for (int r = 0; r < 4; ++r)
        rsum[tr][r] += __shfl_xor(rsum[tr][r], m, 64);

  if (l15 == 0) {
#pragma unroll
    for (int tr = 0; tr < 4; ++tr)
#pragma unroll
      for (int r = 0; r < 4; ++r)
        atomicAdd(&denom[rowg_base + tr * 16 + quad * 4 + r], rsum[tr][r]);
  }

  if (bi != bj) {
#pragma unroll
    for (int m = 16; m <= 32; m <<= 1)
#pragma unroll
      for (int tc = 0; tc < 4; ++tc)
        csum[tc] += __shfl_xor(csum[tc], m, 64);
    if (quad == 0) {
#pragma unroll
      for (int tc = 0; tc < 4; ++tc)
        atomicAdd(&denom[colg_base + tc * 16 + l15], csum[tc]);
    }
  }

  // ---- fused finale: last block computes the loss ----
  __threadfence();   // release: our denom atomics visible before ctr bump
  if (tid == 0) lastflag = (atomicAdd(ctr, 1u) == (unsigned int)(NB - 1));
  __syncthreads();
  if (lastflag) {
    __threadfence();  // acquire: all blocks' denom atomics visible
    float p = 0.0f;
    for (int r = tid; r < M_ROWS; r += 256)
      p += logf(denom[r]) - pos[r & (N_ROWS - 1)] * 10.0f;
#pragma unroll
    for (int m = 32; m >= 1; m >>= 1) p += __shfl_xor(p, m, 64);
    if ((tid & 63) == 0) red[tid >> 6] = p;
    __syncthreads();
    if (tid == 0)
      out[0] = (red[0] + red[1] + red[2] + red[3]) * (1.0f / M_ROWS);
  }
}

extern "C" void kernel_launch(void* const* d_in, const int* in_sizes, int n_in,
                              void* d_out, int out_size, void* d_ws, size_t ws_size,
                              hipStream_t stream) {
  const float* ei = (const float*)d_in[0];
  const float* ej = (const float*)d_in[1];
  float* out = (float*)d_out;

  char* ws = (char*)d_ws;
  u8* reps = (u8*)ws;                                        // 4 MB fp8
  float* denom = (float*)(ws + (size_t)4 * 1024 * 1024);     // 32 KB
  float* pos = (float*)(ws + (size_t)4 * 1024 * 1024 + 32768);        // 16 KB
  unsigned int* ctr = (unsigned int*)(ws + (size_t)4 * 1024 * 1024 + 32768 + 16384);

  norm_kernel<<<N_ROWS / 4, 256, 0, stream>>>(ei, ej, reps, pos, denom, ctr);
  sim_kernel<<<NB, 256, 0, stream>>>(reps, denom, pos, out, ctr);
}

// Round 13
// 236.492 us; speedup vs baseline: 1.0391x; 1.0391x over previous
//
#include <hip/hip_runtime.h>
#include <hip/hip_bf16.h>
#include <math.h>

#define N_ROWS 4096
#define DIM    512            // bytes per fp8 row == elements
#define M_ROWS 8192
// sim GEMM: 128x128 tiles, 4 waves (2x2 of 64x64), FP8 e4m3, BK=64,
// 8 K-steps, 32 KB LDS dbuf, counted-vmcnt loop (round-8 protocol).
// Rows stored KS-INTERLEAVED per 64-B chunk (slot s=ks*4+q at p=q*2+ks) so
// each MFMA fragment pair is ONE ds_read_b128 (round-8's verified pattern).
#define NB     2080           // 64*65/2 triangular tiles (2080 % 8 == 0)
#define NSTEP  8              // 512 / 64
// exp(sim/0.1) = exp2(sim * 10*log2(e))
#define EXP_SCALE 14.4269504088896340736f

typedef unsigned char u8;
typedef __attribute__((ext_vector_type(4))) float f32x4;
typedef __attribute__((ext_vector_type(2))) long l64x2;

// float -> fp8 e4m3fn (OCP), round-to-nearest-even. Inputs finite, |x| <= 1.
__device__ __forceinline__ unsigned int f2e4m3(float x) {
  unsigned int b = __float_as_uint(x);
  unsigned int s = (b >> 24) & 0x80u;
  int e = (int)((b >> 23) & 0xffu);
  unsigned int m = b & 0x7fffffu;
  int ne = e - 127 + 7;                 // target biased exponent
  unsigned int out;
  if (ne >= 1) {                        // normal (|x| >= 2^-6)
    unsigned int q = ((unsigned int)ne << 3) | (m >> 20);
    unsigned int rem = m & 0xfffffu;
    unsigned int rnd = (rem > 0x80000u) || ((rem == 0x80000u) && (q & 1u));
    out = q + rnd;                      // |x|<=1 -> no overflow into NaN
  } else {                              // subnormal / underflow (2^-9 lsb)
    int sh = 21 - ne;
    if (sh > 24) {
      out = 0;
    } else {
      unsigned int full = 0x800000u | m;
      unsigned int q = full >> sh;
      unsigned int rem = full & ((1u << sh) - 1u);
      unsigned int half = 1u << (sh - 1);
      unsigned int rnd = (rem > half) || ((rem == half) && (q & 1u));
      out = q + rnd;
    }
  }
  return s | out;
}

__device__ __forceinline__ unsigned int pack4fp8(float4 v, float s) {
  return f2e4m3(v.x * s) | (f2e4m3(v.y * s) << 8) |
         (f2e4m3(v.z * s) << 16) | (f2e4m3(v.w * s) << 24);
}

// async global -> LDS, 16 B/lane (lds dest = wave-uniform base + lane*16)
__device__ __forceinline__ void async16(const u8* g, u8* l) {
  __builtin_amdgcn_global_load_lds(
      (const __attribute__((address_space(1))) void*)g,
      (__attribute__((address_space(3))) void*)l,
      16, 0, 0);
}

// ---------------------------------------------------------------------------
// Kernel 1: per-row L2 normalize -> fp8 e4m3 reps[8192][512], KS-INTERLEAVED
// within each 64-B k-chunk: source 8-B slot s (k = chunk*64 + s*8) stored at
// slot p = ((s&3)<<1)|(s>>2). Exact fp32 pos[i]. Zeroes denom[] and ctr.
// ---------------------------------------------------------------------------
__global__ __launch_bounds__(256) void norm_kernel(
    const float* __restrict__ ei, const float* __restrict__ ej,
    u8* __restrict__ reps, float* __restrict__ pos,
    float* __restrict__ denom, unsigned int* __restrict__ ctr) {
  int wave = threadIdx.x >> 6;
  int lane = threadIdx.x & 63;
  int b = blockIdx.x * 4 + wave;
  if (blockIdx.x == 0 && threadIdx.x == 0) *ctr = 0u;
  if (lane == 0) {
    denom[b] = 0.0f;
    denom[b + N_ROWS] = 0.0f;
  }
  const float4* pi = (const float4*)(ei + (size_t)b * DIM);
  const float4* pj = (const float4*)(ej + (size_t)b * DIM);
  float4 a0 = pi[lane];
  float4 a1 = pi[lane + 64];
  float4 b0 = pj[lane];
  float4 b1 = pj[lane + 64];

  float si = a0.x*a0.x + a0.y*a0.y + a0.z*a0.z + a0.w*a0.w
           + a1.x*a1.x + a1.y*a1.y + a1.z*a1.z + a1.w*a1.w;
  float sj = b0.x*b0.x + b0.y*b0.y + b0.z*b0.z + b0.w*b0.w
           + b1.x*b1.x + b1.y*b1.y + b1.z*b1.z + b1.w*b1.w;
  float dp = a0.x*b0.x + a0.y*b0.y + a0.z*b0.z + a0.w*b0.w
           + a1.x*b1.x + a1.y*b1.y + a1.z*b1.z + a1.w*b1.w;

#pragma unroll
  for (int m = 32; m >= 1; m >>= 1) {
    si += __shfl_xor(si, m, 64);
    sj += __shfl_xor(sj, m, 64);
    dp += __shfl_xor(dp, m, 64);
  }
  float ii = 1.0f / fmaxf(sqrtf(si), 1e-12f);
  float ij = 1.0f / fmaxf(sqrtf(sj), 1e-12f);
  if (lane == 0) pos[b] = dp * ii * ij;

  // a0 covers k = lane*4..+3: chunk c = lane>>4, slot s = (lane&15)>>1,
  // half h = lane&1, stored slot p = ((s&3)<<1)|(s>>2).
  // dword index = c*16 + p*2 + h ; a1 (k+256) -> chunk c+4, same p,h.
  unsigned int* ri = (unsigned int*)(reps + (size_t)b * DIM);
  unsigned int* rj = (unsigned int*)(reps + (size_t)(b + N_ROWS) * DIM);
  int c = lane >> 4;
  int s = (lane & 15) >> 1;
  int h = lane & 1;
  int p = ((s & 3) << 1) | (s >> 2);
  int d0 = c * 16 + p * 2 + h;
  int d1 = (c + 4) * 16 + p * 2 + h;
  ri[d0] = pack4fp8(a0, ii);
  ri[d1] = pack4fp8(a1, ii);
  rj[d0] = pack4fp8(b0, ij);
  rj[d1] = pack4fp8(b1, ij);
}

// ---------------------------------------------------------------------------
// Kernel 2: 128x128-tile fused FP8 sim-GEMM + exp + masked row/col reduction
// + fused final loss (last block). Round-12 post-mortem: fp8 regression was
// a botched 8-B-granule swizzle (12.8M bank conflicts), not the concept.
// This round: ks-interleaved rows -> each fragment pair is ONE ds_read_b128
// at 16-B-granule XOR swizzle (unit ^= row&3, both sides) -- enumerated
// uniform 8 accesses/bank = b128 floor, conflict-free, structurally equal to
// round 8's 0-conflict reads. Staged bytes HALVED (266 MB) at the same
// 16 waves/CU -> byte-service model predicts sim ~36-50 us.
// Protocol = round 8 (absmax-0 verified): stage-at-top, vmcnt(4), wrap dummy.
// ---------------------------------------------------------------------------
__global__ __launch_bounds__(256) void sim_kernel(
    const u8* __restrict__ reps, float* __restrict__ denom,
    const float* __restrict__ pos, float* __restrict__ out,
    unsigned int* __restrict__ ctr) {
  // chunked XCD remap: XCD x owns logical ids [x*260, (x+1)*260)
  int id = blockIdx.x;
  id = (id & 7) * (NB / 8) + (id >> 3);

  // super-tile blob decode: 4x4 super grid (16x16 tiles each), sj-major,
  // si<=sj; diag super = 136 tiles (16x16 triangle), off-diag = 256.
  int bi, bj;
  {
    int rem = id, Si = 0, Sj = 0, fnd = 0;
    for (int s_j = 0; s_j < 4 && !fnd; ++s_j)
      for (int s_i = 0; s_i <= s_j && !fnd; ++s_i) {
        int sz = (s_i == s_j) ? 136 : 256;
        if (rem < sz) { Si = s_i; Sj = s_j; fnd = 1; }
        else rem -= sz;
      }
    if (Si == Sj) {
      int tj = 0;
      while ((tj + 1) * (tj + 2) / 2 <= rem) ++tj;   // tj <= 15
      int ti = rem - tj * (tj + 1) / 2;
      bi = Si * 16 + ti;
      bj = Sj * 16 + tj;
    } else {
      bi = Si * 16 + (rem & 15);
      bj = Sj * 16 + (rem >> 4);
    }
  }

  __shared__ u8 As[2][8192];   // 8 KB per buffer (128 rows x 64 B)
  __shared__ u8 Bs[2][8192];   // total 32 KB
  __shared__ float red[4];
  __shared__ int lastflag;

  int tid  = threadIdx.x;
  int wave = tid >> 6, lane = tid & 63;
  int wr = wave >> 1, wc = wave & 1;     // 2x2 wave grid, 64x64 each
  int quad = lane >> 4, l15 = lane & 15;

  // staging: chunk c covers LDS bytes [c*1024, +1024) = rows c*16..+15
  // (64 B per row per step). Source 16-B unit pre-swizzled (t ^= srow&3) so
  // the linear LDS dest holds row r's unit u at (u ^ (r&3)).
  int c0 = wave * 2, c1 = c0 + 1;
  int srow = lane >> 2;                        // row within 16-row chunk
  int scol = ((lane & 3) ^ (srow & 3)) * 16;   // swizzled 16-B unit offset
  const u8* gA0 = reps + (size_t)(bi * 128 + c0 * 16 + srow) * DIM + scol;
  const u8* gA1 = reps + (size_t)(bi * 128 + c1 * 16 + srow) * DIM + scol;
  const u8* gB0 = reps + (size_t)(bj * 128 + c0 * 16 + srow) * DIM + scol;
  const u8* gB1 = reps + (size_t)(bj * 128 + c1 * 16 + srow) * DIM + scol;

#define STAGE(D, KC) do {                              \
    int o_ = (KC) * 64;                                \
    async16(gA0 + o_, &As[D][c0 * 1024]);              \
    async16(gA1 + o_, &As[D][c1 * 1024]);              \
    async16(gB0 + o_, &Bs[D][c0 * 1024]);              \
    async16(gB1 + o_, &Bs[D][c1 * 1024]);              \
  } while (0)

  // fragment reads: one b128 per frag. Row = (16-mult)+l15; 16-B unit q
  // swizzled q^(l15&3); low 8 B = ks=0, high 8 B = ks=1 (ks-interleaved).
  int sqr = (quad ^ (l15 & 3)) * 16;
  int abase = (wr * 64 + l15) * 64;
  int bbase = (wc * 64 + l15) * 64;

  f32x4 zero4 = {0.0f, 0.0f, 0.0f, 0.0f};
  f32x4 acc[4][4];
#pragma unroll
  for (int tr = 0; tr < 4; ++tr)
#pragma unroll
    for (int tc = 0; tc < 4; ++tc) acc[tr][tc] = zero4;

  // prologue: stage k-step 0 into buffer 0
  STAGE(0, 0);

  for (int kk = 0; kk < NSTEP; ++kk) {
    int cur = kk & 1;
    int nc = (kk + 1) & 7;   // wrap at kk=7: dummy stage, never read

    STAGE(cur ^ 1, nc);
    asm volatile("s_waitcnt vmcnt(4)" ::: "memory");
    __builtin_amdgcn_s_barrier();   // buf[cur] valid for all waves

    const u8* Ah = &As[cur][0];
    const u8* Bh = &Bs[cur][0];
    l64x2 aF[4], bF[4];
#pragma unroll
    for (int t = 0; t < 4; ++t) {
      aF[t] = *(const l64x2*)(Ah + abase + t * 1024 + sqr);
      bF[t] = *(const l64x2*)(Bh + bbase + t * 1024 + sqr);
    }
    __builtin_amdgcn_s_setprio(1);
#pragma unroll
    for (int tr = 0; tr < 4; ++tr)
#pragma unroll
      for (int tc = 0; tc < 4; ++tc) {
        acc[tr][tc] = __builtin_amdgcn_mfma_f32_16x16x32_fp8_fp8(
            aF[tr][0], bF[tc][0], acc[tr][tc], 0, 0, 0);
        acc[tr][tc] = __builtin_amdgcn_mfma_f32_16x16x32_fp8_fp8(
            aF[tr][1], bF[tc][1], acc[tr][tc], 0, 0, 0);
      }
    __builtin_amdgcn_s_setprio(0);
    __builtin_amdgcn_s_barrier();   // reads of buf[cur] done before overwrite
  }
  // drain the kk=7 dummy stages
  asm volatile("s_waitcnt vmcnt(0)" ::: "memory");

  // ---- epilogue: e = exp(sim/T), mask diagonal, row + col sums ----
  // C/D layout per 16x16 frag (dtype-independent): col=l15, row=quad*4+r
  int rowg_base = bi * 128 + wr * 64;
  int colg_base = bj * 128 + wc * 64;

  f32x4 rsum[4];
  float csum[4] = {0.0f, 0.0f, 0.0f, 0.0f};
#pragma unroll
  for (int tr = 0; tr < 4; ++tr) rsum[tr] = zero4;

#pragma unroll
  for (int tr = 0; tr < 4; ++tr) {
    int rowg0 = rowg_base + tr * 16 + quad * 4;
#pragma unroll
    for (int tc = 0; tc < 4; ++tc) {
      int colg = colg_base + tc * 16 + l15;
      f32x4 a = acc[tr][tc];
      f32x4 e;
#pragma unroll
      for (int r = 0; r < 4; ++r) {
        float v = exp2f(a[r] * EXP_SCALE);
        e[r] = ((rowg0 + r) == colg) ? 0.0f : v;
      }
      rsum[tr] += e;
      csum[tc] += e[0] + e[1] + e[2] + e[3];
    }
  }

#pragma unroll
  for (int m = 1; m <= 8; m <<= 1)
#pragma unroll
    for (int tr = 0; tr < 4; ++tr)
#pragma unroll
      for (int r = 0; r < 4; ++r)
        rsum[tr][r] += __shfl_xor(rsum[tr][r], m, 64);

  if (l15 == 0) {
#pragma unroll
    for (int tr = 0; tr < 4; ++tr)
#pragma unroll
      for (int r = 0; r < 4; ++r)
        atomicAdd(&denom[rowg_base + tr * 16 + quad * 4 + r], rsum[tr][r]);
  }

  if (bi != bj) {
#pragma unroll
    for (int m = 16; m <= 32; m <<= 1)
#pragma unroll
      for (int tc = 0; tc < 4; ++tc)
        csum[tc] += __shfl_xor(csum[tc], m, 64);
    if (quad == 0) {
#pragma unroll
      for (int tc = 0; tc < 4; ++tc)
        atomicAdd(&denom[colg_base + tc * 16 + l15], csum[tc]);
    }
  }

  // ---- fused finale: last block computes the loss ----
  __threadfence();   // release: our denom atomics visible before ctr bump
  if (tid == 0) lastflag = (atomicAdd(ctr, 1u) == (unsigned int)(NB - 1));
  __syncthreads();
  if (lastflag) {
    __threadfence();  // acquire: all blocks' denom atomics visible
    float p = 0.0f;
    for (int r = tid; r < M_ROWS; r += 256)
      p += logf(denom[r]) - pos[r & (N_ROWS - 1)] * 10.0f;
#pragma unroll
    for (int m = 32; m >= 1; m >>= 1) p += __shfl_xor(p, m, 64);
    if ((tid & 63) == 0) red[tid >> 6] = p;
    __syncthreads();
    if (tid == 0)
      out[0] = (red[0] + red[1] + red[2] + red[3]) * (1.0f / M_ROWS);
  }
}

extern "C" void kernel_launch(void* const* d_in, const int* in_sizes, int n_in,
                              void* d_out, int out_size, void* d_ws, size_t ws_size,
                              hipStream_t stream) {
  const float* ei = (const float*)d_in[0];
  const float* ej = (const float*)d_in[1];
  float* out = (float*)d_out;

  char* ws = (char*)d_ws;
  u8* reps = (u8*)ws;                                        // 4 MB fp8
  float* denom = (float*)(ws + (size_t)4 * 1024 * 1024);     // 32 KB
  float* pos = (float*)(ws + (size_t)4 * 1024 * 1024 + 32768);        // 16 KB
  unsigned int* ctr = (unsigned int*)(ws + (size_t)4 * 1024 * 1024 + 32768 + 16384);

  norm_kernel<<<N_ROWS / 4, 256, 0, stream>>>(ei, ej, reps, pos, denom, ctr);
  sim_kernel<<<NB, 256, 0, stream>>>(reps, denom, pos, out, ctr);
}

// Round 15
// 136.146 us; speedup vs baseline: 1.8049x; 1.7370x over previous
//
#include <hip/hip_runtime.h>
#include <hip/hip_bf16.h>
#include <math.h>

#define N_ROWS 4096
#define DIM    512
#define M_ROWS 8192
// sim GEMM: 128x128 tiles, 4 waves (2x2 of 64x64), BK=32, 32 KB LDS dbuf
// -> ~100 VGPR => 4 blocks/CU naturally. Session best-known structure
// (round 8: 136.24 us total, sim 73.2 us, absmax 0).
#define BK     32
#define NTILE  64            // 8192 / 128
#define NB     2080          // 64*65/2 triangular tiles (2080 % 8 == 0)
#define NSTEP  16            // 512 / 32
// exp(sim/0.1) = exp2(sim * 10*log2(e))
#define EXP_SCALE 14.4269504088896340736f

typedef unsigned short ushort_t;
typedef __attribute__((ext_vector_type(8))) short short8;
typedef __attribute__((ext_vector_type(4))) float f32x4;

__device__ __forceinline__ ushort_t f2bf(float x) {
  unsigned int bits = __float_as_uint(x);
  unsigned int lsb = (bits >> 16) & 1u;
  bits += 0x7fffu + lsb;
  return (ushort_t)(bits >> 16);
}

__device__ __forceinline__ void store4bf(ushort_t* p, float4 v, float s) {
  union { ushort_t u[4]; uint2 d; } pk;
  pk.u[0] = f2bf(v.x * s);
  pk.u[1] = f2bf(v.y * s);
  pk.u[2] = f2bf(v.z * s);
  pk.u[3] = f2bf(v.w * s);
  *(uint2*)p = pk.d;
}

// async global -> LDS, 16 B/lane (lds dest = wave-uniform base + lane*16)
__device__ __forceinline__ void async16(const ushort_t* g, ushort_t* l) {
  __builtin_amdgcn_global_load_lds(
      (const __attribute__((address_space(1))) void*)g,
      (__attribute__((address_space(3))) void*)l,
      16, 0, 0);
}

// ---------------------------------------------------------------------------
// Kernel 1: per-row L2 normalize; 256-thread blocks, one wave per row-pair.
// Also zeroes denom[].
// ---------------------------------------------------------------------------
__global__ __launch_bounds__(256) void norm_kernel(
    const float* __restrict__ ei, const float* __restrict__ ej,
    ushort_t* __restrict__ reps, float* __restrict__ pos,
    float* __restrict__ denom) {
  int wave = threadIdx.x >> 6;
  int lane = threadIdx.x & 63;
  int b = blockIdx.x * 4 + wave;
  if (lane == 0) {
    denom[b] = 0.0f;
    denom[b + N_ROWS] = 0.0f;
  }
  const float4* pi = (const float4*)(ei + (size_t)b * DIM);
  const float4* pj = (const float4*)(ej + (size_t)b * DIM);
  float4 a0 = pi[lane];
  float4 a1 = pi[lane + 64];
  float4 b0 = pj[lane];
  float4 b1 = pj[lane + 64];

  float si = a0.x*a0.x + a0.y*a0.y + a0.z*a0.z + a0.w*a0.w
           + a1.x*a1.x + a1.y*a1.y + a1.z*a1.z + a1.w*a1.w;
  float sj = b0.x*b0.x + b0.y*b0.y + b0.z*b0.z + b0.w*b0.w
           + b1.x*b1.x + b1.y*b1.y + b1.z*b1.z + b1.w*b1.w;
  float dp = a0.x*b0.x + a0.y*b0.y + a0.z*b0.z + a0.w*b0.w
           + a1.x*b1.x + a1.y*b1.y + a1.z*b1.z + a1.w*b1.w;

#pragma unroll
  for (int m = 32; m >= 1; m >>= 1) {
    si += __shfl_xor(si, m, 64);
    sj += __shfl_xor(sj, m, 64);
    dp += __shfl_xor(dp, m, 64);
  }
  float ii = 1.0f / fmaxf(sqrtf(si), 1e-12f);
  float ij = 1.0f / fmaxf(sqrtf(sj), 1e-12f);
  if (lane == 0) pos[b] = dp * ii * ij;

  ushort_t* ri = reps + (size_t)b * DIM;
  ushort_t* rj = reps + (size_t)(b + N_ROWS) * DIM;
  store4bf(ri + lane * 4,       a0, ii);
  store4bf(ri + 256 + lane * 4, a1, ii);
  store4bf(rj + lane * 4,       b0, ij);
  store4bf(rj + 256 + lane * 4, b1, ij);
}

// ---------------------------------------------------------------------------
// Kernel 2: 128x128-tile fused sim-GEMM + exp + masked row/col reduction.
// Session-final structure (round 8, best-known):
//  - super-tile blob order (16x16-tile supers, 2-4 MB footprint = one XCD
//    L2) + chunked XCD remap (260 ids/XCD) -> staging is L2-served
//  - counted-vmcnt stage-at-top loop: STAGE(next); vmcnt(4); barrier;
//    reads+MFMA; barrier. Never drains mid-loop. Final step peeled: no
//    dummy stage, vmcnt(0) before the last buffer's reads (saves 16 KB/block
//    of dead traffic vs the wrap-dummy variant; counts stay exact).
//  - both-sides LDS XOR swizzle (slot ^= (row>>1)&3): 0 bank conflicts.
// Eliminated axes (all measured flat or worse at sim ~73 us): tile size,
// staged bytes, cache level, schedule variants, occupancy, source layout,
// fp8. Not a counter-visible roofline; limit of the explored lever set.
// ---------------------------------------------------------------------------
__global__ __launch_bounds__(256) void sim_kernel(
    const ushort_t* __restrict__ reps, float* __restrict__ denom) {
  // chunked XCD remap: XCD x owns logical ids [x*260, (x+1)*260)
  int id = blockIdx.x;
  id = (id & 7) * (NB / 8) + (id >> 3);

  // super-tile blob decode: 4x4 super grid (16x16 tiles each), sj-major,
  // si<=sj; diag super = 136 tiles (16x16 triangle), off-diag = 256.
  int bi, bj;
  {
    int rem = id, Si = 0, Sj = 0, fnd = 0;
    for (int s_j = 0; s_j < 4 && !fnd; ++s_j)
      for (int s_i = 0; s_i <= s_j && !fnd; ++s_i) {
        int sz = (s_i == s_j) ? 136 : 256;
        if (rem < sz) { Si = s_i; Sj = s_j; fnd = 1; }
        else rem -= sz;
      }
    if (Si == Sj) {
      int tj = 0;
      while ((tj + 1) * (tj + 2) / 2 <= rem) ++tj;   // tj <= 15
      int ti = rem - tj * (tj + 1) / 2;
      bi = Si * 16 + ti;
      bj = Sj * 16 + tj;
    } else {
      bi = Si * 16 + (rem & 15);
      bj = Sj * 16 + (rem >> 4);
    }
  }

  __shared__ ushort_t As[2][128 * BK];   // 8 KB per buffer
  __shared__ ushort_t Bs[2][128 * BK];   // total 32 KB -> 4+ blocks/CU by LDS

  int tid  = threadIdx.x;
  int wave = tid >> 6, lane = tid & 63;
  int wr = wave >> 1, wc = wave & 1;     // 2x2 wave grid, 64x64 each
  int quad = lane >> 4, l15 = lane & 15;

  // staging: chunk c covers LDS bytes [c*1024, c*1024+1024) = rows c*16..+15.
  // source col pre-swizzled so the linear LDS dest holds row r's slot s at
  // (s ^ ((r>>1)&3)) -- conflict-free ds_read_b128 (verified: 0 conflicts).
  int c0 = wave * 2, c1 = c0 + 1;
  int srow  = lane >> 2;                               // row within chunk
  int selem = ((lane & 3) ^ ((srow >> 1) & 3)) * 8;    // swizzled elem offset
  const ushort_t* gA0 = reps + (size_t)(bi * 128 + c0 * 16 + srow) * DIM + selem;
  const ushort_t* gA1 = reps + (size_t)(bi * 128 + c1 * 16 + srow) * DIM + selem;
  const ushort_t* gB0 = reps + (size_t)(bj * 128 + c0 * 16 + srow) * DIM + selem;
  const ushort_t* gB1 = reps + (size_t)(bj * 128 + c1 * 16 + srow) * DIM + selem;

#define STAGE(D, KOFF) do {                         \
    async16(gA0 + (KOFF), &As[D][c0 * 512]);        \
    async16(gA1 + (KOFF), &As[D][c1 * 512]);        \
    async16(gB0 + (KOFF), &Bs[D][c0 * 512]);        \
    async16(gB1 + (KOFF), &Bs[D][c1 * 512]);        \
  } while (0)

  // fragment reads: row = (multiple of 16) + l15 -> (row>>1)&3 == (l15>>1)&3
  int sqr = (quad ^ ((l15 >> 1) & 3)) * 8;

  f32x4 zero4 = {0.0f, 0.0f, 0.0f, 0.0f};
  f32x4 acc[4][4];
#pragma unroll
  for (int tr = 0; tr < 4; ++tr)
#pragma unroll
    for (int tc = 0; tc < 4; ++tc) acc[tr][tc] = zero4;

  // prologue: stage k-step 0 into buffer 0
  STAGE(0, 0);

  for (int kk = 0; kk < NSTEP; ++kk) {
    int cur = kk & 1;

    if (kk + 1 < NSTEP) {
      // next step's stage first, then counted wait: the 4 allowed-outstanding
      // are the just-issued loads; step kk's 4 (issued last iter) are
      // confirmed landed without draining the pipeline.
      STAGE(cur ^ 1, (kk + 1) * BK);
      asm volatile("s_waitcnt vmcnt(4)" ::: "memory");
    } else {
      // final step: nothing left to stage; drain the last buffer's loads
      asm volatile("s_waitcnt vmcnt(0)" ::: "memory");
    }
    __builtin_amdgcn_s_barrier();   // buf[cur] valid for all waves

    short8 aF[4], bF[4];
#pragma unroll
    for (int t = 0; t < 4; ++t) {
      aF[t] = *(const short8*)(&As[cur][(wr * 64 + t * 16 + l15) * BK + sqr]);
      bF[t] = *(const short8*)(&Bs[cur][(wc * 64 + t * 16 + l15) * BK + sqr]);
    }
    __builtin_amdgcn_s_setprio(1);
#pragma unroll
    for (int tr = 0; tr < 4; ++tr)
#pragma unroll
      for (int tc = 0; tc < 4; ++tc)
        acc[tr][tc] = __builtin_amdgcn_mfma_f32_16x16x32_bf16(
            aF[tr], bF[tc], acc[tr][tc], 0, 0, 0);
    __builtin_amdgcn_s_setprio(0);
    __builtin_amdgcn_s_barrier();   // all reads of buf[cur] done before its
                                    // overwrite (staged next iteration)
  }

  // ---- epilogue: e = exp(sim/T), mask diagonal, row + col sums ----
  // C layout per 16x16 frag: col = l15, row = quad*4 + r  [m89/m91]
  int rowg_base = bi * 128 + wr * 64;
  int colg_base = bj * 128 + wc * 64;

  f32x4 rsum[4];
  float csum[4] = {0.0f, 0.0f, 0.0f, 0.0f};
#pragma unroll
  for (int tr = 0; tr < 4; ++tr) rsum[tr] = zero4;

#pragma unroll
  for (int tr = 0; tr < 4; ++tr) {
    int rowg0 = rowg_base + tr * 16 + quad * 4;
#pragma unroll
    for (int tc = 0; tc < 4; ++tc) {
      int colg = colg_base + tc * 16 + l15;
      f32x4 a = acc[tr][tc];
      f32x4 e;
#pragma unroll
      for (int r = 0; r < 4; ++r) {
        float v = exp2f(a[r] * EXP_SCALE);
        e[r] = ((rowg0 + r) == colg) ? 0.0f : v;
      }
      rsum[tr] += e;
      csum[tc] += e[0] + e[1] + e[2] + e[3];
    }
  }

  // reduce row sums across the 16 lanes sharing `quad` (masks 1,2,4,8)
#pragma unroll
  for (int m = 1; m <= 8; m <<= 1)
#pragma unroll
    for (int tr = 0; tr < 4; ++tr)
#pragma unroll
      for (int r = 0; r < 4; ++r)
        rsum[tr][r] += __shfl_xor(rsum[tr][r], m, 64);

  if (l15 == 0) {
#pragma unroll
    for (int tr = 0; tr < 4; ++tr)
#pragma unroll
      for (int r = 0; r < 4; ++r)
        atomicAdd(&denom[rowg_base + tr * 16 + quad * 4 + r], rsum[tr][r]);
  }

  if (bi != bj) {
    // reduce col sums across quads (masks 16,32)
#pragma unroll
    for (int m = 16; m <= 32; m <<= 1)
#pragma unroll
      for (int tc = 0; tc < 4; ++tc)
        csum[tc] += __shfl_xor(csum[tc], m, 64);
    if (quad == 0) {
#pragma unroll
      for (int tc = 0; tc < 4; ++tc)
        atomicAdd(&denom[colg_base + tc * 16 + l15], csum[tc]);
    }
  }
}

// ---------------------------------------------------------------------------
// Kernel 3: loss = mean over rows of [log(denom) - pos/T]
// ---------------------------------------------------------------------------
__global__ __launch_bounds__(1024) void loss_kernel(
    const float* __restrict__ denom, const float* __restrict__ pos,
    float* __restrict__ out) {
  __shared__ float red[16];
  int tid = threadIdx.x;
  float p = 0.0f;
  for (int r = tid; r < M_ROWS; r += 1024)
    p += logf(denom[r]) - pos[r & (N_ROWS - 1)] * 10.0f;
#pragma unroll
  for (int m = 32; m >= 1; m >>= 1) p += __shfl_xor(p, m, 64);
  if ((tid & 63) == 0) red[tid >> 6] = p;
  __syncthreads();
  if (tid == 0) {
    float s = 0.0f;
#pragma unroll
    for (int i = 0; i < 16; ++i) s += red[i];
    out[0] = s * (1.0f / M_ROWS);
  }
}

extern "C" void kernel_launch(void* const* d_in, const int* in_sizes, int n_in,
                              void* d_out, int out_size, void* d_ws, size_t ws_size,
                              hipStream_t stream) {
  const float* ei = (const float*)d_in[0];
  const float* ej = (const float*)d_in[1];
  float* out = (float*)d_out;

  char* ws = (char*)d_ws;
  ushort_t* reps = (ushort_t*)ws;                                   // 8 MB bf16
  float* denom = (float*)(ws + (size_t)M_ROWS * DIM * 2);           // 32 KB
  float* pos = (float*)(ws + (size_t)M_ROWS * DIM * 2 + M_ROWS * 4);// 16 KB

  norm_kernel<<<N_ROWS / 4, 256, 0, stream>>>(ei, ej, reps, pos, denom);
  sim_kernel<<<NB, 256, 0, stream>>>(reps, denom);
  loss_kernel<<<1, 1024, 0, stream>>>(denom, pos, out);
}

// Round 16
// 132.211 us; speedup vs baseline: 1.8586x; 1.0298x over previous
//
#include <hip/hip_runtime.h>
#include <hip/hip_bf16.h>
#include <math.h>

#define N_ROWS 4096
#define DIM    512
#define M_ROWS 8192
// sim GEMM: 128x128 tiles, 4 waves (2x2 of 64x64), BK=32, WAVE-PRIVATE LDS,
// ZERO barriers. Discriminating experiment: every round 0-15 variant kept
// block-wide barriers (sim pinned 72-82 us); this removes them entirely at
// the cost of 2x staged bytes (waves no longer share panels).
#define BK     32
#define NTILE  64            // 8192 / 128
#define NB     2080          // 64*65/2 triangular tiles (2080 % 8 == 0)
#define NSTEP  16            // 512 / 32
// exp(sim/0.1) = exp2(sim * 10*log2(e))
#define EXP_SCALE 14.4269504088896340736f

typedef unsigned short ushort_t;
typedef __attribute__((ext_vector_type(8))) short short8;
typedef __attribute__((ext_vector_type(4))) float f32x4;

__device__ __forceinline__ ushort_t f2bf(float x) {
  unsigned int bits = __float_as_uint(x);
  unsigned int lsb = (bits >> 16) & 1u;
  bits += 0x7fffu + lsb;
  return (ushort_t)(bits >> 16);
}

__device__ __forceinline__ void store4bf(ushort_t* p, float4 v, float s) {
  union { ushort_t u[4]; uint2 d; } pk;
  pk.u[0] = f2bf(v.x * s);
  pk.u[1] = f2bf(v.y * s);
  pk.u[2] = f2bf(v.z * s);
  pk.u[3] = f2bf(v.w * s);
  *(uint2*)p = pk.d;
}

// async global -> LDS, 16 B/lane (lds dest = wave-uniform base + lane*16)
__device__ __forceinline__ void async16(const ushort_t* g, ushort_t* l) {
  __builtin_amdgcn_global_load_lds(
      (const __attribute__((address_space(1))) void*)g,
      (__attribute__((address_space(3))) void*)l,
      16, 0, 0);
}

// ---------------------------------------------------------------------------
// Kernel 1: per-row L2 normalize; 256-thread blocks, one wave per row-pair.
// Also zeroes denom[]. (Unchanged, verified.)
// ---------------------------------------------------------------------------
__global__ __launch_bounds__(256) void norm_kernel(
    const float* __restrict__ ei, const float* __restrict__ ej,
    ushort_t* __restrict__ reps, float* __restrict__ pos,
    float* __restrict__ denom) {
  int wave = threadIdx.x >> 6;
  int lane = threadIdx.x & 63;
  int b = blockIdx.x * 4 + wave;
  if (lane == 0) {
    denom[b] = 0.0f;
    denom[b + N_ROWS] = 0.0f;
  }
  const float4* pi = (const float4*)(ei + (size_t)b * DIM);
  const float4* pj = (const float4*)(ej + (size_t)b * DIM);
  float4 a0 = pi[lane];
  float4 a1 = pi[lane + 64];
  float4 b0 = pj[lane];
  float4 b1 = pj[lane + 64];

  float si = a0.x*a0.x + a0.y*a0.y + a0.z*a0.z + a0.w*a0.w
           + a1.x*a1.x + a1.y*a1.y + a1.z*a1.z + a1.w*a1.w;
  float sj = b0.x*b0.x + b0.y*b0.y + b0.z*b0.z + b0.w*b0.w
           + b1.x*b1.x + b1.y*b1.y + b1.z*b1.z + b1.w*b1.w;
  float dp = a0.x*b0.x + a0.y*b0.y + a0.z*b0.z + a0.w*b0.w
           + a1.x*b1.x + a1.y*b1.y + a1.z*b1.z + a1.w*b1.w;

#pragma unroll
  for (int m = 32; m >= 1; m >>= 1) {
    si += __shfl_xor(si, m, 64);
    sj += __shfl_xor(sj, m, 64);
    dp += __shfl_xor(dp, m, 64);
  }
  float ii = 1.0f / fmaxf(sqrtf(si), 1e-12f);
  float ij = 1.0f / fmaxf(sqrtf(sj), 1e-12f);
  if (lane == 0) pos[b] = dp * ii * ij;

  ushort_t* ri = reps + (size_t)b * DIM;
  ushort_t* rj = reps + (size_t)(b + N_ROWS) * DIM;
  store4bf(ri + lane * 4,       a0, ii);
  store4bf(ri + 256 + lane * 4, a1, ii);
  store4bf(rj + lane * 4,       b0, ij);
  store4bf(rj + 256 + lane * 4, b1, ij);
}

// ---------------------------------------------------------------------------
// Kernel 2: 128x128-tile fused sim-GEMM + exp + masked row/col reduction.
// BARRIER-FREE: each wave owns a private 16 KB LDS slice (2 dbuf x (4 KB A +
// 4 KB B)) and stages its own 64-row panels. No s_barrier in the kernel.
// Correctness (wave-local only):
//  RAW: loop-top issues 8 stage loads for buf[nxt], then vmcnt(8) -> the 8
//       issued LAST iteration (into buf[cur]) are confirmed landed.
//  WAR: ds_reads of buf[cur] retire (lgkmcnt) before their consuming MFMAs
//       issue, which precede next iteration's stage of buf[cur] in program
//       order -> no overwrite-before-read.
// Keeps: super-tile blob order + chunked XCD remap (L2-served staging),
// both-sides XOR swizzle (identical geometry to r8's 0-conflict reads).
// Cost: 2x staged bytes (~1.06 GB) -- the discriminating variable.
// ---------------------------------------------------------------------------
__global__ __launch_bounds__(256) void sim_kernel(
    const ushort_t* __restrict__ reps, float* __restrict__ denom) {
  // chunked XCD remap: XCD x owns logical ids [x*260, (x+1)*260)
  int id = blockIdx.x;
  id = (id & 7) * (NB / 8) + (id >> 3);

  // super-tile blob decode: 4x4 super grid (16x16 tiles each), sj-major,
  // si<=sj; diag super = 136 tiles (16x16 triangle), off-diag = 256.
  int bi, bj;
  {
    int rem = id, Si = 0, Sj = 0, fnd = 0;
    for (int s_j = 0; s_j < 4 && !fnd; ++s_j)
      for (int s_i = 0; s_i <= s_j && !fnd; ++s_i) {
        int sz = (s_i == s_j) ? 136 : 256;
        if (rem < sz) { Si = s_i; Sj = s_j; fnd = 1; }
        else rem -= sz;
      }
    if (Si == Sj) {
      int tj = 0;
      while ((tj + 1) * (tj + 2) / 2 <= rem) ++tj;   // tj <= 15
      int ti = rem - tj * (tj + 1) / 2;
      bi = Si * 16 + ti;
      bj = Sj * 16 + tj;
    } else {
      bi = Si * 16 + (rem & 15);
      bj = Sj * 16 + (rem >> 4);
    }
  }

  // wave-private LDS: [wave][dbuf][A(2048) | B(2048)] ushorts = 64 KB total
  __shared__ ushort_t Wl[4][2][4096];

  int tid  = threadIdx.x;
  int wave = tid >> 6, lane = tid & 63;
  int wr = wave >> 1, wc = wave & 1;     // 2x2 wave grid, 64x64 each
  int quad = lane >> 4, l15 = lane & 15;

  // staging: this wave stages its own 64 A-rows (wr half) and 64 B-rows
  // (wc half); 4 async16 each (16 rows x 64 B = 1 KB per instr).
  // Source col pre-swizzled so linear LDS holds row r's slot s at
  // (s ^ ((r>>1)&3)) -- same verified geometry as round 8 (0 conflicts).
  int srow  = lane >> 2;                               // row within 16-chunk
  int selem = ((lane & 3) ^ ((srow >> 1) & 3)) * 8;    // swizzled elem offset
  const ushort_t* gA0 = reps + (size_t)(bi * 128 + wr * 64 +  0 + srow) * DIM + selem;
  const ushort_t* gA1 = reps + (size_t)(bi * 128 + wr * 64 + 16 + srow) * DIM + selem;
  const ushort_t* gA2 = reps + (size_t)(bi * 128 + wr * 64 + 32 + srow) * DIM + selem;
  const ushort_t* gA3 = reps + (size_t)(bi * 128 + wr * 64 + 48 + srow) * DIM + selem;
  const ushort_t* gB0 = reps + (size_t)(bj * 128 + wc * 64 +  0 + srow) * DIM + selem;
  const ushort_t* gB1 = reps + (size_t)(bj * 128 + wc * 64 + 16 + srow) * DIM + selem;
  const ushort_t* gB2 = reps + (size_t)(bj * 128 + wc * 64 + 32 + srow) * DIM + selem;
  const ushort_t* gB3 = reps + (size_t)(bj * 128 + wc * 64 + 48 + srow) * DIM + selem;

#define STAGE_W(D, KOFF) do {                         \
    ushort_t* b_ = &Wl[wave][D][0];                   \
    async16(gA0 + (KOFF), b_);                        \
    async16(gA1 + (KOFF), b_ + 512);                  \
    async16(gA2 + (KOFF), b_ + 1024);                 \
    async16(gA3 + (KOFF), b_ + 1536);                 \
    async16(gB0 + (KOFF), b_ + 2048);                 \
    async16(gB1 + (KOFF), b_ + 2560);                 \
    async16(gB2 + (KOFF), b_ + 3072);                 \
    async16(gB3 + (KOFF), b_ + 3584);                 \
  } while (0)

  // fragment reads: row = t*16 + l15 within the wave's private 64-row panel;
  // (row>>1)&3 == (l15>>1)&3 -> swizzled slot uniform per lane.
  int sqr = (quad ^ ((l15 >> 1) & 3)) * 8;

  f32x4 zero4 = {0.0f, 0.0f, 0.0f, 0.0f};
  f32x4 acc[4][4];
#pragma unroll
  for (int tr = 0; tr < 4; ++tr)
#pragma unroll
    for (int tc = 0; tc < 4; ++tc) acc[tr][tc] = zero4;

  // prologue: stage k-step 0 into buffer 0 (8 loads outstanding)
  STAGE_W(0, 0);

  for (int kk = 0; kk < NSTEP; ++kk) {
    int cur = kk & 1;

    if (kk + 1 < NSTEP) {
      STAGE_W(cur ^ 1, (kk + 1) * BK);                 // 8 new loads
      asm volatile("s_waitcnt vmcnt(8)" ::: "memory"); // prior 8 landed
    } else {
      asm volatile("s_waitcnt vmcnt(0)" ::: "memory"); // drain final buffer
    }
    // NO barrier: LDS slice is wave-private.

    const ushort_t* Ab = &Wl[wave][cur][0];
    const ushort_t* Bb = &Wl[wave][cur][2048];
    short8 aF[4], bF[4];
#pragma unroll
    for (int t = 0; t < 4; ++t) {
      aF[t] = *(const short8*)(Ab + (t * 16 + l15) * BK + sqr);
      bF[t] = *(const short8*)(Bb + (t * 16 + l15) * BK + sqr);
    }
    __builtin_amdgcn_s_setprio(1);
#pragma unroll
    for (int tr = 0; tr < 4; ++tr)
#pragma unroll
      for (int tc = 0; tc < 4; ++tc)
        acc[tr][tc] = __builtin_amdgcn_mfma_f32_16x16x32_bf16(
            aF[tr], bF[tc], acc[tr][tc], 0, 0, 0);
    __builtin_amdgcn_s_setprio(0);
    // NO barrier: WAR handled by program order + lgkmcnt retirement.
  }

  // ---- epilogue: e = exp(sim/T), mask diagonal, row + col sums ----
  // C layout per 16x16 frag: col = l15, row = quad*4 + r  [m89/m91]
  int rowg_base = bi * 128 + wr * 64;
  int colg_base = bj * 128 + wc * 64;

  f32x4 rsum[4];
  float csum[4] = {0.0f, 0.0f, 0.0f, 0.0f};
#pragma unroll
  for (int tr = 0; tr < 4; ++tr) rsum[tr] = zero4;

#pragma unroll
  for (int tr = 0; tr < 4; ++tr) {
    int rowg0 = rowg_base + tr * 16 + quad * 4;
#pragma unroll
    for (int tc = 0; tc < 4; ++tc) {
      int colg = colg_base + tc * 16 + l15;
      f32x4 a = acc[tr][tc];
      f32x4 e;
#pragma unroll
      for (int r = 0; r < 4; ++r) {
        float v = exp2f(a[r] * EXP_SCALE);
        e[r] = ((rowg0 + r) == colg) ? 0.0f : v;
      }
      rsum[tr] += e;
      csum[tc] += e[0] + e[1] + e[2] + e[3];
    }
  }

  // reduce row sums across the 16 lanes sharing `quad` (masks 1,2,4,8)
#pragma unroll
  for (int m = 1; m <= 8; m <<= 1)
#pragma unroll
    for (int tr = 0; tr < 4; ++tr)
#pragma unroll
      for (int r = 0; r < 4; ++r)
        rsum[tr][r] += __shfl_xor(rsum[tr][r], m, 64);

  if (l15 == 0) {
#pragma unroll
    for (int tr = 0; tr < 4; ++tr)
#pragma unroll
      for (int r = 0; r < 4; ++r)
        atomicAdd(&denom[rowg_base + tr * 16 + quad * 4 + r], rsum[tr][r]);
  }

  if (bi != bj) {
    // reduce col sums across quads (masks 16,32)
#pragma unroll
    for (int m = 16; m <= 32; m <<= 1)
#pragma unroll
      for (int tc = 0; tc < 4; ++tc)
        csum[tc] += __shfl_xor(csum[tc], m, 64);
    if (quad == 0) {
#pragma unroll
      for (int tc = 0; tc < 4; ++tc)
        atomicAdd(&denom[colg_base + tc * 16 + l15], csum[tc]);
    }
  }
}

// ---------------------------------------------------------------------------
// Kernel 3: loss = mean over rows of [log(denom) - pos/T]
// ---------------------------------------------------------------------------
__global__ __launch_bounds__(1024) void loss_kernel(
    const float* __restrict__ denom, const float* __restrict__ pos,
    float* __restrict__ out) {
  __shared__ float red[16];
  int tid = threadIdx.x;
  float p = 0.0f;
  for (int r = tid; r < M_ROWS; r += 1024)
    p += logf(denom[r]) - pos[r & (N_ROWS - 1)] * 10.0f;
#pragma unroll
  for (int m = 32; m >= 1; m >>= 1) p += __shfl_xor(p, m, 64);
  if ((tid & 63) == 0) red[tid >> 6] = p;
  __syncthreads();
  if (tid == 0) {
    float s = 0.0f;
#pragma unroll
    for (int i = 0; i < 16; ++i) s += red[i];
    out[0] = s * (1.0f / M_ROWS);
  }
}

extern "C" void kernel_launch(void* const* d_in, const int* in_sizes, int n_in,
                              void* d_out, int out_size, void* d_ws, size_t ws_size,
                              hipStream_t stream) {
  const float* ei = (const float*)d_in[0];
  const float* ej = (const float*)d_in[1];
  float* out = (float*)d_out;

  char* ws = (char*)d_ws;
  ushort_t* reps = (ushort_t*)ws;                                   // 8 MB bf16
  float* denom = (float*)(ws + (size_t)M_ROWS * DIM * 2);           // 32 KB
  float* pos = (float*)(ws + (size_t)M_ROWS * DIM * 2 + M_ROWS * 4);// 16 KB

  norm_kernel<<<N_ROWS / 4, 256, 0, stream>>>(ei, ej, reps, pos, denom);
  sim_kernel<<<NB, 256, 0, stream>>>(reps, denom);
  loss_kernel<<<1, 1024, 0, stream>>>(denom, pos, out);
}